// Round 8
// baseline (276.521 us; speedup 1.0000x reference)
//
#include <hip/hip_runtime.h>
#include <cstdint>
#include <cstddef>

typedef unsigned short u16;
typedef __attribute__((ext_vector_type(8))) short bf16x8;
typedef __attribute__((ext_vector_type(4))) float f32x4;
typedef __attribute__((ext_vector_type(16))) float f32x16;

#define EPI_F32 0
#define EPI_BF16_RELU 1
#define EPI_QKV 2
#define EPI_PART 3

// 1/sqrt(64) * log2(e): QK^T scores come out in log2 domain -> exp2 softmax
#define QSCALE 0.18033688011112042f

__device__ __forceinline__ u16 f2bf(float f) {
  uint32_t u = __float_as_uint(f);
  return (u16)((u + 0x7FFFu + ((u >> 16) & 1u)) >> 16);
}

__device__ __forceinline__ uint32_t cvt_pk_bf16(float lo, float hi) {
  uint32_t r;
  asm("v_cvt_pk_bf16_f32 %0, %1, %2" : "=v"(r) : "v"(lo), "v"(hi));
  return r;
}

__device__ __forceinline__ float fexp2(float x) { return __builtin_amdgcn_exp2f(x); }

__device__ __forceinline__ void gload_lds16(const void* g, void* l) {
  __builtin_amdgcn_global_load_lds((const __attribute__((address_space(1))) void*)g,
                                   (__attribute__((address_space(3))) void*)l, 16, 0, 0);
}

// ------------------------------ fused prep kernel --------------------------------
__device__ __forceinline__ void tcvt_tile(const float* __restrict__ W,
                                          u16* __restrict__ Wt, int K, int N,
                                          int bx, int by, float (*tl)[33], int t) {
  const int kr0 = by * 32, nc0 = bx * 32;
  const int r = t >> 3, cq = (t & 7) * 4;
  float4 v = *(const float4*)&W[(size_t)(kr0 + r) * N + nc0 + cq];
  tl[r][cq + 0] = v.x; tl[r][cq + 1] = v.y; tl[r][cq + 2] = v.z; tl[r][cq + 3] = v.w;
  __syncthreads();
  union { u16 u[4]; uint2 q; } pk;
#pragma unroll
  for (int j = 0; j < 4; ++j) pk.u[j] = f2bf(tl[cq + j][r]);
  *(uint2*)&Wt[(size_t)(nc0 + r) * K + kr0 + cq] = pk.q;
}

__global__ __launch_bounds__(256) void prep_kernel(
    const float* __restrict__ x, u16* __restrict__ xb,
    const float* __restrict__ Wq, const float* __restrict__ Wk,
    const float* __restrict__ Wv, const float* __restrict__ Wo,
    u16* __restrict__ Wqkvt, u16* __restrict__ Wot,
    const float* __restrict__ W1, u16* __restrict__ W1t,
    const float* __restrict__ W2, u16* __restrict__ W2t,
    const float* __restrict__ bq, const float* __restrict__ bk,
    const float* __restrict__ bv, float* __restrict__ bqkv) {
  __shared__ float tl[32][33];
  const int b = blockIdx.x, t = threadIdx.x;
  if (b < 2048) {
    const int i = b * 256 + t;
    const float4* p = (const float4*)x + (size_t)i * 2;
    float4 a = p[0], c = p[1];
    union { u16 u[8]; uint4 q; } pk;
    pk.u[0] = f2bf(a.x); pk.u[1] = f2bf(a.y); pk.u[2] = f2bf(a.z); pk.u[3] = f2bf(a.w);
    pk.u[4] = f2bf(c.x); pk.u[5] = f2bf(c.y); pk.u[6] = f2bf(c.z); pk.u[7] = f2bf(c.w);
    ((uint4*)xb)[i] = pk.q;
  } else if (b < 3072) {
    const int u = b - 2048, z = u >> 8, s = u & 255;
    const float* W = z == 0 ? Wq : (z == 1 ? Wk : (z == 2 ? Wv : Wo));
    u16* Wt = z < 3 ? Wqkvt + z * 262144 : Wot;
    tcvt_tile(W, Wt, 512, 512, s & 15, s >> 4, tl, t);
  } else if (b < 4096) {
    const int u = b - 3072;
    tcvt_tile(W1, W1t, 512, 2048, u % 64, u / 64, tl, t);
  } else if (b < 5120) {
    const int u = b - 4096;
    tcvt_tile(W2, W2t, 2048, 512, u % 16, u / 16, tl, t);
  } else {
    const int i = (b - 5120) * 256 + t;
    if (i < 1536) bqkv[i] = i < 512 ? bq[i] : (i < 1024 ? bk[i - 512] : bv[i - 1024]);
  }
}

// -------------- gemm3: wave-private LDS pipeline, ZERO barriers ------------------
// 128x128 tile, 4 waves (2x2), wave owns 64x64. Each wave stages ITS OWN 64-row
// A/B panel slices (BK=32) into a private 16KB LDS region (double-buffered,
// 2-deep prefetch). No wave reads LDS written by another wave -> no syncthreads.
// Per-wave in-order issue + lgkmcnt(0) resolves WAR; vmcnt(8) waits tile t's 8
// loads (oldest-first semantics, m135). Swizzle slot^(row&3) on global source,
// same XOR on read (rule 21). Panels staged twice (2 waves share each) -> 2x L2
// traffic, fine (L2 ceiling ~1100TF at this intensity).
template<int EPI, int SPLIT>
__global__ __launch_bounds__(256, 2) void gemm3_kernel(
    const u16* __restrict__ A, const u16* __restrict__ Bt,
    const float* __restrict__ bias, void* __restrict__ out,
    int M, int N, int K) {
  __shared__ u16 lds[32768];  // 64KB: [wave][A b0|A b1|B b0|B b1] x 2048 u16
  const int tid = threadIdx.x, lane = tid & 63, wave = tid >> 6;
  const int m0 = blockIdx.y * 128, n0 = blockIdx.x * 128;
  const int wm = wave >> 1, wn = wave & 1;
  const int g = lane >> 4, lr = lane & 15;
  const int rs = lr & 3;
  u16* wl = &lds[wave * 8192];

  // staging: lane l covers (row = i*16 + (l>>2), slot = l&3); global k-offset of
  // slot s at row r is (s^(r&3))*8 so the linear LDS write equals swizzled layout
  const int soff = (((lane & 3) ^ ((lane >> 2) & 3)) << 3);
  const u16* Ab = A + (size_t)(m0 + wm * 64 + (lane >> 2)) * K + soff;
  const u16* Bb = Bt + (size_t)(n0 + wn * 64 + (lane >> 2)) * K + soff;

#define ST3(buf, k0) do {                                                  \
    _Pragma("unroll") for (int i_ = 0; i_ < 4; ++i_)                       \
      gload_lds16(Ab + (size_t)(i_ * 16) * K + (k0),                       \
                  &wl[(buf) * 2048 + i_ * 512 + lane * 8]);                \
    _Pragma("unroll") for (int i_ = 0; i_ < 4; ++i_)                       \
      gload_lds16(Bb + (size_t)(i_ * 16) * K + (k0),                       \
                  &wl[4096 + (buf) * 2048 + i_ * 512 + lane * 8]);         \
  } while (0)

  f32x4 acc[4][4] = {};
  const int kBeg = (SPLIT > 1) ? blockIdx.z * (K / SPLIT) : 0;
  const int NT = ((SPLIT > 1) ? K / SPLIT : K) >> 5;

  ST3(0, kBeg);
  ST3(1, kBeg + 32);

  for (int t = 0; t < NT; ++t) {
    const int buf = t & 1;
    if (t + 1 < NT) { asm volatile("s_waitcnt vmcnt(8)" ::: "memory"); }
    else            { asm volatile("s_waitcnt vmcnt(0)" ::: "memory"); }
    bf16x8 af[4], bfr[4];
#pragma unroll
    for (int mi = 0; mi < 4; ++mi)
      af[mi] = *(const bf16x8*)&wl[buf * 2048 + (mi * 16 + lr) * 32 + ((g ^ rs) << 3)];
#pragma unroll
    for (int ni = 0; ni < 4; ++ni)
      bfr[ni] = *(const bf16x8*)&wl[4096 + buf * 2048 + (ni * 16 + lr) * 32 + ((g ^ rs) << 3)];
    asm volatile("s_waitcnt lgkmcnt(0)" ::: "memory");  // frags in regs; buf free
    __builtin_amdgcn_sched_barrier(0);                  // rule 18: pin the wait
    if (t + 2 < NT) ST3(buf, kBeg + (t + 2) * 32);      // restage freed buffer
    __builtin_amdgcn_s_setprio(1);
#pragma unroll
    for (int mi = 0; mi < 4; ++mi)
#pragma unroll
      for (int ni = 0; ni < 4; ++ni)
        acc[mi][ni] = __builtin_amdgcn_mfma_f32_16x16x32_bf16(af[mi], bfr[ni],
                                                              acc[mi][ni], 0, 0, 0);
    __builtin_amdgcn_s_setprio(0);
  }
#undef ST3

  // epilogue: D layout col=lane&15, row=(lane>>4)*4+reg  [m89-verified]
#pragma unroll
  for (int mi = 0; mi < 4; ++mi) {
#pragma unroll
    for (int ni = 0; ni < 4; ++ni) {
      const int col = n0 + wn * 64 + ni * 16 + lr;
      const float bv = (EPI == EPI_PART) ? 0.f : bias[col];
      f32x4 v = acc[mi][ni];
#pragma unroll
      for (int r = 0; r < 4; ++r) {
        const int row = m0 + wm * 64 + mi * 16 + g * 4 + r;
        const float y = v[r] + bv;
        if (EPI == EPI_F32) {
          ((float*)out)[(size_t)row * N + col] = y;
        } else if (EPI == EPI_PART) {
          ((float*)out)[(size_t)blockIdx.z * M * N + (size_t)row * N + col] = y;
        } else if (EPI == EPI_BF16_RELU) {
          ((u16*)out)[(size_t)row * N + col] = f2bf(fmaxf(y, 0.f));
        } else {  // EPI_QKV
          u16* qb = (u16*)out;
          const int sec = col >> 9, cs = col & 511;
          const int b = row >> 10, tt = row & 1023, h = cs >> 6, d = cs & 63;
          if (sec == 0)
            qb[((size_t)((b * 8 + h) * 1024 + tt)) * 64 + d] = f2bf(y * QSCALE);
          else if (sec == 1)
            qb[4194304 + ((size_t)((b * 8 + h) * 1024 + tt)) * 64 + d] = f2bf(y);
          else
            qb[8388608 + ((size_t)((b * 8 + h) * 64 + d)) * 1024 + tt] = f2bf(y);
        }
      }
    }
  }
}

// ------------- flash attention v4: LDS-staged K/V, double-buffered ---------------
__global__ __launch_bounds__(256, 2) void attn4_kernel(
    const u16* __restrict__ Q, const u16* __restrict__ K,
    const u16* __restrict__ Vt, u16* __restrict__ ctx) {
  __shared__ u16 smem[16384];
  const int tid = threadIdx.x, lane = tid & 63, w = tid >> 6;
  const int bh = blockIdx.x >> 3, qb = blockIdx.x & 7;
  const int c = lane & 31, g = lane >> 5;
  const int q0 = qb * 128 + w * 32;

  const u16* Qp = Q + ((size_t)bh * 1024 + q0 + c) * 64 + g * 8;
  const bf16x8 qf0 = *(const bf16x8*)(Qp);
  const bf16x8 qf1 = *(const bf16x8*)(Qp + 16);
  const bf16x8 qf2 = *(const bf16x8*)(Qp + 32);
  const bf16x8 qf3 = *(const bf16x8*)(Qp + 48);

  const u16* Kbase = K + (size_t)bh * 65536;
  const u16* Vbase = Vt + (size_t)bh * 65536;

  const int r0 = w * 16 + (lane >> 3), r1 = r0 + 8;
  const int cg0 = ((lane & 7) ^ (r0 & 7)) << 3;
  const int cg1 = ((lane & 7) ^ (r1 & 7)) << 3;

#define STAGE(buf, key0) do {                                                       \
    gload_lds16(Kbase + (size_t)((key0) + r0) * 64 + cg0, &smem[(buf)*4096 + w*1024]);       \
    gload_lds16(Kbase + (size_t)((key0) + r1) * 64 + cg1, &smem[(buf)*4096 + w*1024 + 512]); \
    gload_lds16(Vbase + (size_t)r0 * 1024 + (key0) + cg0, &smem[8192 + (buf)*4096 + w*1024]);\
    gload_lds16(Vbase + (size_t)r1 * 1024 + (key0) + cg1, &smem[8192 + (buf)*4096 + w*1024 + 512]); \
  } while (0)

  const int cs = c & 7;
  const int ro0 = c * 64, ro1 = (32 + c) * 64;
#define KS(buf, ro, cg) (*(const bf16x8*)&smem[(buf)*4096 + (ro) + ((((cg)) ^ cs) << 3)])
#define VS(buf, ro, cg) (*(const bf16x8*)&smem[8192 + (buf)*4096 + (ro) + ((((cg)) ^ cs) << 3)])

  f32x16 cacc[2] = {};
  float mrun = -1e30f, lrun = 0.f;

  STAGE(0, 0);
  __syncthreads();

  for (int kt = 0; kt < 16; ++kt) {
    const int buf = kt & 1;
    if (kt < 15) STAGE(buf ^ 1, (kt + 1) * 64);

    const bf16x8 kf0 = KS(buf, ro0, g),     kf1 = KS(buf, ro0, 2 + g);
    const bf16x8 kf2 = KS(buf, ro0, 4 + g), kf3 = KS(buf, ro0, 6 + g);
    const bf16x8 kf4 = KS(buf, ro1, g),     kf5 = KS(buf, ro1, 2 + g);
    const bf16x8 kf6 = KS(buf, ro1, 4 + g), kf7 = KS(buf, ro1, 6 + g);

    f32x16 sa = {}, sb = {};
    sa = __builtin_amdgcn_mfma_f32_32x32x16_bf16(kf0, qf0, sa, 0, 0, 0);
    sb = __builtin_amdgcn_mfma_f32_32x32x16_bf16(kf4, qf0, sb, 0, 0, 0);
    sa = __builtin_amdgcn_mfma_f32_32x32x16_bf16(kf1, qf1, sa, 0, 0, 0);
    sb = __builtin_amdgcn_mfma_f32_32x32x16_bf16(kf5, qf1, sb, 0, 0, 0);
    sa = __builtin_amdgcn_mfma_f32_32x32x16_bf16(kf2, qf2, sa, 0, 0, 0);
    sb = __builtin_amdgcn_mfma_f32_32x32x16_bf16(kf6, qf2, sb, 0, 0, 0);
    sa = __builtin_amdgcn_mfma_f32_32x32x16_bf16(kf3, qf3, sa, 0, 0, 0);
    sb = __builtin_amdgcn_mfma_f32_32x32x16_bf16(kf7, qf3, sb, 0, 0, 0);

    float tm[16];
#pragma unroll
    for (int r = 0; r < 16; ++r) tm[r] = fmaxf(sa[r], sb[r]);
#pragma unroll
    for (int st = 8; st >= 1; st >>= 1)
#pragma unroll
      for (int r = 0; r < st; ++r) tm[r] = fmaxf(tm[r], tm[r + st]);
    const float mt = fmaxf(tm[0], __shfl_xor(tm[0], 32));
    if (!__all(mt <= mrun)) {
      const float mnew = fmaxf(mrun, mt);
      const float al = fexp2(mrun - mnew);
#pragma unroll
      for (int r = 0; r < 16; ++r) { cacc[0][r] *= al; cacc[1][r] *= al; }
      lrun *= al;
      mrun = mnew;
    }
    float pa[16], pb[16];
#pragma unroll
    for (int r = 0; r < 16; ++r) pa[r] = fexp2(sa[r] - mrun);
#pragma unroll
    for (int r = 0; r < 16; ++r) pb[r] = fexp2(sb[r] - mrun);
    float ts[16];
#pragma unroll
    for (int r = 0; r < 16; ++r) ts[r] = pa[r] + pb[r];
#pragma unroll
    for (int st = 8; st >= 1; st >>= 1)
#pragma unroll
      for (int r = 0; r < st; ++r) ts[r] += ts[r + st];
    lrun += ts[0] + __shfl_xor(ts[0], 32);

    uint32_t wda[8], pwa[8], wdb[8], pwb[8];
#pragma unroll
    for (int i = 0; i < 8; ++i) wda[i] = cvt_pk_bf16(pa[2 * i], pa[2 * i + 1]);
#pragma unroll
    for (int i = 0; i < 8; ++i) wdb[i] = cvt_pk_bf16(pb[2 * i], pb[2 * i + 1]);
#pragma unroll
    for (int i = 0; i < 8; ++i) pwa[i] = __shfl_xor((int)wda[i], 32);
#pragma unroll
    for (int i = 0; i < 8; ++i) pwb[i] = __shfl_xor((int)wdb[i], 32);
    union { uint32_t u[4]; bf16x8 v; } b0a, b1a, b0b, b1b;
    const bool glo = (g == 0);
    b0a.u[0] = glo ? wda[0] : pwa[2]; b0a.u[1] = glo ? wda[1] : pwa[3];
    b0a.u[2] = glo ? pwa[0] : wda[2]; b0a.u[3] = glo ? pwa[1] : wda[3];
    b1a.u[0] = glo ? wda[4] : pwa[6]; b1a.u[1] = glo ? wda[5] : pwa[7];
    b1a.u[2] = glo ? pwa[4] : wda[6]; b1a.u[3] = glo ? pwa[5] : wda[7];
    b0b.u[0] = glo ? wdb[0] : pwb[2]; b0b.u[1] = glo ? wdb[1] : pwb[3];
    b0b.u[2] = glo ? pwb[0] : wdb[2]; b0b.u[3] = glo ? pwb[1] : wdb[3];
    b1b.u[0] = glo ? wdb[4] : pwb[6]; b1b.u[1] = glo ? wdb[5] : pwb[7];
    b1b.u[2] = glo ? pwb[4] : wdb[6]; b1b.u[3] = glo ? pwb[5] : wdb[7];

    const bf16x8 va00 = VS(buf, ro0, g),     va01 = VS(buf, ro0, 2 + g);
    const bf16x8 vb00 = VS(buf, ro0, 4 + g), vb01 = VS(buf, ro0, 6 + g);
    const bf16x8 va10 = VS(buf, ro1, g),     va11 = VS(buf, ro1, 2 + g);
    const bf16x8 vb10 = VS(buf, ro1, 4 + g), vb11 = VS(buf, ro1, 6 + g);

    cacc[0] = __builtin_amdgcn_mfma_f32_32x32x16_bf16(va00, b0a.v, cacc[0], 0, 0, 0);
    cacc[1] = __builtin_amdgcn_mfma_f32_32x32x16_bf16(va10, b0a.v, cacc[1], 0, 0, 0);
    cacc[0] = __builtin_amdgcn_mfma_f32_32x32x16_bf16(va01, b1a.v, cacc[0], 0, 0, 0);
    cacc[1] = __builtin_amdgcn_mfma_f32_32x32x16_bf16(va11, b1a.v, cacc[1], 0, 0, 0);
    cacc[0] = __builtin_amdgcn_mfma_f32_32x32x16_bf16(vb00, b0b.v, cacc[0], 0, 0, 0);
    cacc[1] = __builtin_amdgcn_mfma_f32_32x32x16_bf16(vb10, b0b.v, cacc[1], 0, 0, 0);
    cacc[0] = __builtin_amdgcn_mfma_f32_32x32x16_bf16(vb01, b1b.v, cacc[0], 0, 0, 0);
    cacc[1] = __builtin_amdgcn_mfma_f32_32x32x16_bf16(vb11, b1b.v, cacc[1], 0, 0, 0);

    __syncthreads();
  }

  const float inv = 1.0f / lrun;
  u16* tw = &smem[w * 2048];
#pragma unroll
  for (int h2 = 0; h2 < 2; ++h2) {
#pragma unroll
    for (int rq = 0; rq < 4; ++rq) {
      const u16 x0 = f2bf(cacc[h2][4 * rq + 0] * inv);
      const u16 x1 = f2bf(cacc[h2][4 * rq + 1] * inv);
      const u16 x2 = f2bf(cacc[h2][4 * rq + 2] * inv);
      const u16 x3 = f2bf(cacc[h2][4 * rq + 3] * inv);
      uint2 val;
      val.x = (uint32_t)x0 | ((uint32_t)x1 << 16);
      val.y = (uint32_t)x2 | ((uint32_t)x3 << 16);
      const int chunk = h2 * 4 + rq;
      *(uint2*)&tw[c * 64 + ((chunk ^ (c & 7)) * 8) + 4 * g] = val;
    }
  }
  __syncthreads();
  const int b_ = bh >> 3, h_ = bh & 7;
#pragma unroll
  for (int t = 0; t < 4; ++t) {
    const int lcg = t * 256 + tid;
    const int wv = lcg >> 8, rem = lcg & 255;
    const int q = rem >> 3, cg = rem & 7;
    const uint4 val = *(const uint4*)&smem[wv * 2048 + q * 64 + ((cg ^ (q & 7)) * 8)];
    const int grow = qb * 128 + wv * 32 + q;
    *(uint4*)&ctx[((size_t)(b_ * 1024 + grow)) * 512 + h_ * 64 + cg * 8] = val;
  }
#undef STAGE
#undef KS
#undef VS
}

// ------- residual + split-K-combine + layernorm (1 wave per 512-col row) --------
template<bool ABF16>
__global__ __launch_bounds__(256) void lnc_kernel(
    const void* __restrict__ Av, const float* __restrict__ P0,
    const float* __restrict__ P1, const float* __restrict__ pb,
    const float* __restrict__ gw, const float* __restrict__ bw,
    float* __restrict__ outF, u16* __restrict__ outB) {
  const int lane = threadIdx.x & 63, wave = threadIdx.x >> 6;
  const int row = blockIdx.x * 4 + wave;
  float a[8];
  if (ABF16) {
    const uint4 q = ((const uint4*)((const u16*)Av + (size_t)row * 512))[lane];
    const u16* pu = (const u16*)&q;
#pragma unroll
    for (int j = 0; j < 8; ++j) a[j] = __uint_as_float((uint32_t)pu[j] << 16);
  } else {
    const float4* a4 = (const float4*)((const float*)Av + (size_t)row * 512);
    const float4 x0 = a4[lane * 2], x1 = a4[lane * 2 + 1];
    a[0] = x0.x; a[1] = x0.y; a[2] = x0.z; a[3] = x0.w;
    a[4] = x1.x; a[5] = x1.y; a[6] = x1.z; a[7] = x1.w;
  }
  const float4* p04 = (const float4*)(P0 + (size_t)row * 512);
  const float4* p14 = (const float4*)(P1 + (size_t)row * 512);
  const float4 q00 = p04[lane * 2], q01 = p04[lane * 2 + 1];
  const float4 q10 = p14[lane * 2], q11 = p14[lane * 2 + 1];
  const float4 e0 = ((const float4*)pb)[lane * 2], e1 = ((const float4*)pb)[lane * 2 + 1];
  float v[8] = {a[0] + q00.x + q10.x + e0.x, a[1] + q00.y + q10.y + e0.y,
                a[2] + q00.z + q10.z + e0.z, a[3] + q00.w + q10.w + e0.w,
                a[4] + q01.x + q11.x + e1.x, a[5] + q01.y + q11.y + e1.y,
                a[6] + q01.z + q11.z + e1.z, a[7] + q01.w + q11.w + e1.w};
  float s = 0.f;
#pragma unroll
  for (int j = 0; j < 8; ++j) s += v[j];
#pragma unroll
  for (int off = 32; off >= 1; off >>= 1) s += __shfl_xor(s, off);
  const float mu = s * (1.f / 512.f);
  float vs = 0.f;
#pragma unroll
  for (int j = 0; j < 8; ++j) { const float d = v[j] - mu; vs += d * d; }
#pragma unroll
  for (int off = 32; off >= 1; off >>= 1) vs += __shfl_xor(vs, off);
  const float rstd = rsqrtf(vs * (1.f / 512.f) + 1e-5f);
  const float4 gA = ((const float4*)gw)[lane * 2], gB = ((const float4*)gw)[lane * 2 + 1];
  const float4 bA = ((const float4*)bw)[lane * 2], bB = ((const float4*)bw)[lane * 2 + 1];
  const float og[8] = {gA.x, gA.y, gA.z, gA.w, gB.x, gB.y, gB.z, gB.w};
  const float ob[8] = {bA.x, bA.y, bA.z, bA.w, bB.x, bB.y, bB.z, bB.w};
  float o[8];
#pragma unroll
  for (int j = 0; j < 8; ++j) o[j] = (v[j] - mu) * rstd * og[j] + ob[j];
  if (outF) {
    float4 w0 = {o[0], o[1], o[2], o[3]}, w1 = {o[4], o[5], o[6], o[7]};
    ((float4*)(outF + (size_t)row * 512))[lane * 2] = w0;
    ((float4*)(outF + (size_t)row * 512))[lane * 2 + 1] = w1;
  }
  if (outB) {
    union { u16 u[8]; uint4 q; } pk;
#pragma unroll
    for (int j = 0; j < 8; ++j) pk.u[j] = f2bf(o[j]);
    ((uint4*)(outB + (size_t)row * 512))[lane] = pk.q;
  }
}

// --------------------------------- launch ---------------------------------------
extern "C" void kernel_launch(void* const* d_in, const int* in_sizes, int n_in,
                              void* d_out, int out_size, void* d_ws, size_t ws_size,
                              hipStream_t stream) {
  const float* x   = (const float*)d_in[0];
  const float* Wq  = (const float*)d_in[1];
  const float* bq  = (const float*)d_in[2];
  const float* Wk  = (const float*)d_in[3];
  const float* bk  = (const float*)d_in[4];
  const float* Wv  = (const float*)d_in[5];
  const float* bv  = (const float*)d_in[6];
  const float* Wo  = (const float*)d_in[7];
  const float* bo  = (const float*)d_in[8];
  const float* g1  = (const float*)d_in[9];
  const float* b1  = (const float*)d_in[10];
  const float* g2  = (const float*)d_in[11];
  const float* b2  = (const float*)d_in[12];
  const float* W1  = (const float*)d_in[13];
  const float* bf1 = (const float*)d_in[14];
  const float* W2  = (const float*)d_in[15];
  const float* bf2 = (const float*)d_in[16];

  char* ws = (char*)d_ws;
  u16*   xb    = (u16*)(ws + 0);           // [8192][512] bf16
  u16*   Wqkvt = (u16*)(ws + 8388608);     // [1536][512] bf16
  u16*   Wot   = (u16*)(ws + 9961472);     // [512][512]
  u16*   W1t   = (u16*)(ws + 10485760);    // [2048][512]
  u16*   W2t   = (u16*)(ws + 12582912);    // [512][2048]
  u16*   Qb    = (u16*)(ws + 14680064);    // [BH][1024][64]; Kb,Vtb follow
  u16*   ctx   = (u16*)(ws + 39845888);    // [8192][512] bf16
  float* P0    = (float*)(ws + 48234496);  // [8192][512] f32 partial (P1 follows)
  u16*   h1b   = (u16*)(ws + 81788928);    // [8192][512] bf16
  u16*   mid   = (u16*)(ws + 14680064);    // [8192][2048] bf16 (over Qb..ctx, dead)
  float* bqkv  = (float*)(ws + 39845888);  // 1536 f32 (over ctx, dead before attn)

  prep_kernel<<<5126, 256, 0, stream>>>(x, xb, Wq, Wk, Wv, Wo, Wqkvt, Wot,
                                        W1, W1t, W2, W2t, bq, bk, bv, bqkv);

  // fused QKV projection (Q pre-scaled by 1/sqrt(D)*log2e)
  gemm3_kernel<EPI_QKV, 1><<<dim3(12, 64), 256, 0, stream>>>(
      xb, Wqkvt, bqkv, Qb, 8192, 1536, 512);

  attn4_kernel<<<512, 256, 0, stream>>>(Qb, Qb + 4194304, Qb + 8388608, ctx);

  // Wo: split-K x2 partials; LN1 combines xb + P0 + P1 + bo -> h1b (bf16)
  gemm3_kernel<EPI_PART, 2><<<dim3(4, 64, 2), 256, 0, stream>>>(
      ctx, Wot, nullptr, P0, 8192, 512, 512);
  lnc_kernel<true><<<2048, 256, 0, stream>>>(xb, P0, P0 + 4194304, bo, g1, b1,
                                             nullptr, h1b);

  // FFN1
  gemm3_kernel<EPI_BF16_RELU, 1><<<dim3(16, 64), 256, 0, stream>>>(
      h1b, W1t, bf1, mid, 8192, 2048, 512);

  // FFN2: split-K x2 partials; LN2 combines h1b + P0 + P1 + bf2 -> d_out (f32)
  gemm3_kernel<EPI_PART, 2><<<dim3(4, 64, 2), 256, 0, stream>>>(
      mid, W2t, nullptr, P0, 8192, 512, 2048);
  lnc_kernel<true><<<2048, 256, 0, stream>>>(h1b, P0, P0 + 4194304, bf2, g2, b2,
                                             (float*)d_out, nullptr);
}